// Round 1
// baseline (2411.320 us; speedup 1.0000x reference)
//
#include <hip/hip_runtime.h>
#include <hip/hip_bf16.h>

// Problem constants
#define NB 4
#define NC 256
#define NH_ 8
#define LPOOL 1024          // 32*32
constexpr float EPSV = 1e-5f;

// workspace offsets (in floats)
#define OFF_P   0u                  // pooled/normed: 2*4*256*1024 = 2,097,152
#define OFF_Q   2097152u            // 1,048,576 each
#define OFF_K   3145728u
#define OFF_V1  4194304u
#define OFF_V2  5242880u
#define OFF_M1  6291456u
#define OFF_M2  7340032u
#define OFF_MG  8388608u
#define OFF_A   9437184u            // RegionA: 33,554,432 floats (scores -> z -> o)
#define OFF_HID 42991616u           // hidden bf16: 33,554,432 ushorts (16,777,216 float slots)

__device__ __forceinline__ float bf16_to_f(unsigned short u) {
    union { unsigned int ui; float f; } t; t.ui = ((unsigned int)u) << 16; return t.f;
}
__device__ __forceinline__ unsigned short f_to_bf16(float f) {
    union { float f; unsigned int u; } t; t.f = f;
    unsigned int u = t.u;
    u += 0x7fffu + ((u >> 16) & 1u);
    return (unsigned short)(u >> 16);
}

// ---------------- maxpool 4x4 (both branches) ----------------
__global__ __launch_bounds__(256) void pool_kernel(const float* __restrict__ x1,
                                                   const float* __restrict__ x2,
                                                   float* __restrict__ pooled) {
    int idx = blockIdx.x * 256 + threadIdx.x;           // 2^21 total
    int j = idx & 31, i = (idx >> 5) & 31, c = (idx >> 10) & 255, n = (idx >> 18) & 3, br = idx >> 20;
    const float* xp = br ? x2 : x1;
    const float* base = xp + (((size_t)(n * 256 + c) * 128 + i * 4) * 128 + j * 4);
    float m = -3.4e38f;
#pragma unroll
    for (int r = 0; r < 4; ++r) {
        float4 v = *(const float4*)(base + r * 128);
        m = fmaxf(m, fmaxf(fmaxf(v.x, v.y), fmaxf(v.z, v.w)));
    }
    pooled[(size_t)br * 1048576 + (size_t)(n * 256 + c) * 1024 + i * 32 + j] = m;
}

// ---------------- LayerNorm over channel dim, in place ----------------
__global__ __launch_bounds__(256) void lnc_kernel(float* __restrict__ p,
                                                  const float* __restrict__ g,
                                                  const float* __restrict__ b) {
    int bid = blockIdx.x;                                // (br,n,l)
    int l = bid & 1023, n = (bid >> 10) & 3, br = bid >> 12;
    int c = threadIdx.x;
    size_t idx = (size_t)br * 1048576 + (size_t)(n * 256 + c) * 1024 + l;
    float v = p[idx];
    __shared__ float red[256];
    red[c] = v; __syncthreads();
    for (int off = 128; off > 0; off >>= 1) { if (c < off) red[c] += red[c + off]; __syncthreads(); }
    float mean = red[0] / 256.f;
    __syncthreads();
    float d = v - mean;
    red[c] = d * d; __syncthreads();
    for (int off = 128; off > 0; off >>= 1) { if (c < off) red[c] += red[c + off]; __syncthreads(); }
    float var = red[0] / 256.f;
    float rstd = rsqrtf(var + EPSV);
    p[idx] = (v - mean) * rstd * g[c] + b[c];
}

// ---------------- depthwise 3x3 conv + BN; writes heads layout [n][l][c] ----------------
__global__ __launch_bounds__(256) void dwbn_kernel(const float* __restrict__ p,
    const float* __restrict__ qkw, const float* __restrict__ qkg, const float* __restrict__ qkb,
    const float* __restrict__ qkm, const float* __restrict__ qkv,
    const float* __restrict__ vw, const float* __restrict__ vg, const float* __restrict__ vb,
    const float* __restrict__ vm, const float* __restrict__ vv,
    float* __restrict__ qkvbuf) {
    int which = blockIdx.y;                        // 0:q(p1,qk) 1:k(p2,qk) 2:v1(p1,v) 3:v2(p2,v)
    int flat = blockIdx.x * 256 + threadIdx.x;     // 2^20
    int l = flat & 1023, c = (flat >> 10) & 255, n = flat >> 18;
    int br = which & 1;
    const float* w  = (which < 2) ? qkw : vw;
    const float* g  = (which < 2) ? qkg : vg;
    const float* bb = (which < 2) ? qkb : vb;
    const float* rm = (which < 2) ? qkm : vm;
    const float* rv = (which < 2) ? qkv : vv;
    int i = l >> 5, j = l & 31;
    const float* pin = p + (size_t)br * 1048576 + (size_t)(n * 256 + c) * 1024;
    float acc = 0.f;
#pragma unroll
    for (int ky = -1; ky <= 1; ++ky) {
        int yy = i + ky;
        if ((unsigned)yy < 32u) {
#pragma unroll
            for (int kx = -1; kx <= 1; ++kx) {
                int xx = j + kx;
                if ((unsigned)xx < 32u)
                    acc += pin[yy * 32 + xx] * w[c * 9 + (ky + 1) * 3 + (kx + 1)];
            }
        }
    }
    float sc = g[c] * rsqrtf(rv[c] + EPSV);
    qkvbuf[(size_t)which * 1048576 + (size_t)(n * 1024 + l) * 256 + c] = sc * (acc - rm[c]) + bb[c];
}

// ---------------- scores[n][h][l][s] = t * sum_d q*k ----------------
__global__ __launch_bounds__(256) void qk_kernel(const float* __restrict__ q,
                                                 const float* __restrict__ k,
                                                 float* __restrict__ scores) {
    int lt = blockIdx.x, st = blockIdx.y, n = blockIdx.z;
    int l0 = lt * 32, s0 = st * 32;
    int tid = threadIdx.x;
    const float tsc = 0.17677669529663687f;   // 1/sqrt(32)
    __shared__ float Qs[128][34];
    __shared__ float Ks[128][34];
    float acc[2][2][8];
#pragma unroll
    for (int i = 0; i < 2; ++i)
#pragma unroll
        for (int j = 0; j < 2; ++j)
#pragma unroll
            for (int h = 0; h < 8; ++h) acc[i][j][h] = 0.f;
    int ty = tid >> 4, tx = tid & 15;
#pragma unroll
    for (int ch = 0; ch < 2; ++ch) {
        int cbase = ch * 128;
        for (int it = 0; it < 16; ++it) {
            int li = it * 2 + (tid >> 7);
            int cl = tid & 127;
            Qs[cl][li] = tsc * q[(size_t)(n * 1024 + l0 + li) * 256 + cbase + cl];
            Ks[cl][li] = k[(size_t)(n * 1024 + s0 + li) * 256 + cbase + cl];
        }
        __syncthreads();
#pragma unroll
        for (int h8 = 0; h8 < 4; ++h8) {
            for (int c2 = 0; c2 < 32; ++c2) {
                int cl = h8 * 32 + c2;
                float2 qv = *(const float2*)&Qs[cl][ty * 2];
                float2 kv = *(const float2*)&Ks[cl][tx * 2];
                acc[0][0][ch * 4 + h8] += qv.x * kv.x;
                acc[0][1][ch * 4 + h8] += qv.x * kv.y;
                acc[1][0][ch * 4 + h8] += qv.y * kv.x;
                acc[1][1][ch * 4 + h8] += qv.y * kv.y;
            }
        }
        __syncthreads();
    }
#pragma unroll
    for (int h = 0; h < 8; ++h)
#pragma unroll
        for (int i = 0; i < 2; ++i) {
            size_t o = ((size_t)(n * 8 + h) * 1024 + l0 + ty * 2 + i) * 1024 + s0 + tx * 2;
            *(float2*)&scores[o] = make_float2(acc[i][0][h], acc[i][1][h]);
        }
}

// ---------------- m1[n,l,h,d] = sum_s softmax_s(sc)[l,s] * v2[s, h*32+d] ----------------
__global__ __launch_bounds__(256) void m1_kernel(const float* __restrict__ scores,
                                                 const float* __restrict__ v2,
                                                 float* __restrict__ m1out) {
    int lt = blockIdx.x, h = blockIdx.y, n = blockIdx.z;
    int l0 = lt * 32, tid = threadIdx.x;
    const float* sb = scores + (size_t)(n * 8 + h) * 1024 * 1024;
    __shared__ float red[32][9];
    __shared__ float rowmax[32], rowinv[32];
    __shared__ float wls[32][36];   // [ss][l]
    __shared__ float v2s[32][36];   // [ss][d]
    int li = tid >> 3, sg = tid & 7;
    float pm = -3.4e38f;
    for (int s = sg; s < 1024; s += 8) pm = fmaxf(pm, sb[(size_t)(l0 + li) * 1024 + s]);
    red[li][sg] = pm; __syncthreads();
    if (sg == 0) { float m = red[li][0]; for (int t = 1; t < 8; ++t) m = fmaxf(m, red[li][t]); rowmax[li] = m; }
    __syncthreads();
    float rmx = rowmax[li];
    float ps = 0.f;
    for (int s = sg; s < 1024; s += 8) ps += expf(sb[(size_t)(l0 + li) * 1024 + s] - rmx);
    red[li][sg] = ps; __syncthreads();
    if (sg == 0) { float s = 0; for (int t = 0; t < 8; ++t) s += red[li][t]; rowinv[li] = 1.f / s; }
    __syncthreads();
    float rinv = rowinv[li];
    int lg = tid >> 5, d = tid & 31;
    float a0 = 0, a1 = 0, a2 = 0, a3 = 0;
    int ssi = tid >> 3, dg = tid & 7;
    for (int s0c = 0; s0c < 1024; s0c += 32) {
        float4 vvv = *(const float4*)&v2[(size_t)(n * 1024 + s0c + ssi) * 256 + h * 32 + dg * 4];
        *(float4*)&v2s[ssi][dg * 4] = vvv;
        for (int ss = sg; ss < 32; ss += 8) {
            float v = sb[(size_t)(l0 + li) * 1024 + s0c + ss];
            wls[ss][li] = expf(v - rmx) * rinv;
        }
        __syncthreads();
#pragma unroll 8
        for (int ss = 0; ss < 32; ++ss) {
            float v2v = v2s[ss][d];
            float4 w4 = *(const float4*)&wls[ss][lg * 4];
            a0 += w4.x * v2v; a1 += w4.y * v2v; a2 += w4.z * v2v; a3 += w4.w * v2v;
        }
        __syncthreads();
    }
    size_t ob = (size_t)(n * 1024 + l0 + lg * 4) * 256 + h * 32 + d;
    m1out[ob] = a0; m1out[ob + 256] = a1; m1out[ob + 512] = a2; m1out[ob + 768] = a3;
}

// ---------------- m2[n,s,h,d] = sum_l softmax_h(sc)[l,s,h] * v1[l, h*32+d] ----------------
__global__ __launch_bounds__(256) void m2_kernel(const float* __restrict__ scores,
                                                 const float* __restrict__ v1,
                                                 float* __restrict__ m2out) {
    int st = blockIdx.x, lc = blockIdx.y, n = blockIdx.z;
    int s0 = st * 32, tid = threadIdx.x;
    int h = tid >> 5, si = tid & 31;
    __shared__ float scs[8][36];
    __shared__ float es[8][36];
    float acc[32];
#pragma unroll
    for (int i = 0; i < 32; ++i) acc[i] = 0.f;
    int lend = lc * 256 + 256;
    for (int l = lc * 256; l < lend; ++l) {
        float sc = scores[((size_t)(n * 8 + h) * 1024 + l) * 1024 + s0 + si];
        scs[h][si] = sc;
        __syncthreads();
        float mx = scs[0][si];
#pragma unroll
        for (int hh = 1; hh < 8; ++hh) mx = fmaxf(mx, scs[hh][si]);
        float e = expf(sc - mx);
        es[h][si] = e;
        __syncthreads();
        float ssum = es[0][si];
#pragma unroll
        for (int hh = 1; hh < 8; ++hh) ssum += es[hh][si];
        scs[h][si] = e / ssum;
        __syncthreads();
        float v1v = v1[(size_t)(n * 1024 + l) * 256 + tid];
#pragma unroll
        for (int ss = 0; ss < 32; ss += 4) {
            float4 w4 = *(const float4*)&scs[h][ss];
            acc[ss] += w4.x * v1v; acc[ss + 1] += w4.y * v1v;
            acc[ss + 2] += w4.z * v1v; acc[ss + 3] += w4.w * v1v;
        }
        __syncthreads();
    }
#pragma unroll
    for (int ss = 0; ss < 32; ++ss)
        atomicAdd(&m2out[(size_t)(n * 1024 + s0 + ss) * 256 + tid], acc[ss]);
}

// ---------------- merged[n,l,c] = sum_c' m[n,l,c'] * merge_w[c,c'] ----------------
__global__ __launch_bounds__(256) void merge_kernel(const float* __restrict__ m,
                                                    const float* __restrict__ mw,
                                                    float* __restrict__ merged) {
    int bid = blockIdx.x;
    int n = bid >> 7, lt = bid & 127;
    int l0 = lt * 8, tid = threadIdx.x;
    __shared__ float ms[8][260];
#pragma unroll
    for (int r = 0; r < 8; ++r) ms[r][tid] = m[(size_t)(n * 1024 + l0 + r) * 256 + tid];
    __syncthreads();
    float acc[8];
#pragma unroll
    for (int r = 0; r < 8; ++r) acc[r] = 0.f;
    const float4* wrow = (const float4*)(mw + (size_t)tid * 256);
    for (int c4 = 0; c4 < 64; ++c4) {
        float4 w4 = wrow[c4];
#pragma unroll
        for (int r = 0; r < 8; ++r) {
            float4 m4 = *(const float4*)&ms[r][c4 * 4];
            acc[r] += w4.x * m4.x + w4.y * m4.y + w4.z * m4.z + w4.w * m4.w;
        }
    }
#pragma unroll
    for (int r = 0; r < 8; ++r)
        merged[(size_t)(n * 1024 + l0 + r) * 256 + tid] = acc[r];
}

// ---------------- z[pix][512] = concat(x NHWC, bilinear-up(merged)) ----------------
__global__ __launch_bounds__(256) void zbuild_kernel(const float* __restrict__ x,
                                                     const float* __restrict__ merged,
                                                     float* __restrict__ z) {
    int pix0 = blockIdx.x * 32;
    int n = pix0 >> 14, y = (pix0 >> 7) & 127, x0 = pix0 & 127;
    int tid = threadIdx.x;
    int ci = tid >> 5, xi = tid & 31;
    __shared__ float xs[256][33];
    for (int cc = 0; cc < 32; ++cc) {
        int c = cc * 8 + ci;
        xs[c][xi] = x[((size_t)(n * 256 + c) * 128 + y) * 128 + x0 + xi];
    }
    __syncthreads();
    float iy = y * 0.25f - 0.375f;
    int y0i = (int)floorf(iy);
    float fy = iy - (float)y0i;
    int y0c = max(y0i, 0), y1c = min(y0i + 1, 31);
    const float* mb = merged + (size_t)n * 1024 * 256;
    for (int xj = 0; xj < 32; ++xj) {
        size_t zb = (size_t)(pix0 + xj) * 512;
        z[zb + tid] = xs[tid][xj];
        int xx = x0 + xj;
        float ix = xx * 0.25f - 0.375f;
        int x0i = (int)floorf(ix);
        float fx = ix - (float)x0i;
        int x0cc = max(x0i, 0), x1cc = min(x0i + 1, 31);
        float v00 = mb[(size_t)(y0c * 32 + x0cc) * 256 + tid];
        float v01 = mb[(size_t)(y0c * 32 + x1cc) * 256 + tid];
        float v10 = mb[(size_t)(y1c * 32 + x0cc) * 256 + tid];
        float v11 = mb[(size_t)(y1c * 32 + x1cc) * 256 + tid];
        float v = (1.f - fy) * ((1.f - fx) * v00 + fx * v01) + fy * ((1.f - fx) * v10 + fx * v11);
        z[zb + 256 + tid] = v;
    }
}

// ---------------- generic fp32 GEMM: C[M,N] = act(A[M,512] @ W[N,512]^T) ----------------
__global__ __launch_bounds__(256) void gemm_kernel(const float* __restrict__ Af,
                                                   const unsigned short* __restrict__ Ah,
                                                   const float* __restrict__ W,
                                                   float* __restrict__ Of,
                                                   unsigned short* __restrict__ Oh,
                                                   int N, int doRelu) {
    const int K = 512;
    int m0 = blockIdx.x * 64, n0 = blockIdx.y * 64;
    int tid = threadIdx.x;
    int tx = tid & 15, ty = tid >> 4;
    __shared__ float As[16][68], Bs[16][68];
    float acc[4][4];
#pragma unroll
    for (int i = 0; i < 4; ++i)
#pragma unroll
        for (int j = 0; j < 4; ++j) acc[i][j] = 0.f;
    int kk = tid & 15, rr = tid >> 4;
    for (int k0 = 0; k0 < K; k0 += 16) {
#pragma unroll
        for (int p = 0; p < 4; ++p) {
            int r = rr + p * 16;
            float av;
            if (Ah) av = bf16_to_f(Ah[(size_t)(m0 + r) * K + k0 + kk]);
            else    av = Af[(size_t)(m0 + r) * K + k0 + kk];
            As[kk][r] = av;
            Bs[kk][r] = W[(size_t)(n0 + r) * K + k0 + kk];
        }
        __syncthreads();
#pragma unroll
        for (int kx2 = 0; kx2 < 16; ++kx2) {
            float4 a = *(const float4*)&As[kx2][ty * 4];
            float4 b = *(const float4*)&Bs[kx2][tx * 4];
            acc[0][0] += a.x * b.x; acc[0][1] += a.x * b.y; acc[0][2] += a.x * b.z; acc[0][3] += a.x * b.w;
            acc[1][0] += a.y * b.x; acc[1][1] += a.y * b.y; acc[1][2] += a.y * b.z; acc[1][3] += a.y * b.w;
            acc[2][0] += a.z * b.x; acc[2][1] += a.z * b.y; acc[2][2] += a.z * b.z; acc[2][3] += a.z * b.w;
            acc[3][0] += a.w * b.x; acc[3][1] += a.w * b.y; acc[3][2] += a.w * b.z; acc[3][3] += a.w * b.w;
        }
        __syncthreads();
    }
#pragma unroll
    for (int i = 0; i < 4; ++i) {
        size_t ob = (size_t)(m0 + ty * 4 + i) * N + n0 + tx * 4;
        float o0 = acc[i][0], o1 = acc[i][1], o2 = acc[i][2], o3 = acc[i][3];
        if (doRelu) {
            o0 = fmaxf(o0, 0.f); o1 = fmaxf(o1, 0.f); o2 = fmaxf(o2, 0.f); o3 = fmaxf(o3, 0.f);
        }
        if (Oh) {
            ushort4 h4; h4.x = f_to_bf16(o0); h4.y = f_to_bf16(o1); h4.z = f_to_bf16(o2); h4.w = f_to_bf16(o3);
            *(ushort4*)&Oh[ob] = h4;
        } else {
            *(float4*)&Of[ob] = make_float4(o0, o1, o2, o3);
        }
    }
}

// ---------------- LN over channels + residual + NCHW write ----------------
__global__ __launch_bounds__(256) void final_kernel(const float* __restrict__ o,
                                                    const float* __restrict__ xin,
                                                    const float* __restrict__ g,
                                                    const float* __restrict__ b,
                                                    float* __restrict__ outp) {
    int xg = blockIdx.x, y = blockIdx.y, n = blockIdx.z;
    int x0 = xg * 32;
    int pix0 = (n * 128 + y) * 128 + x0;
    int tid = threadIdx.x;
    __shared__ float zf[32][257];
    for (int j = 0; j < 32; ++j) zf[j][tid] = o[(size_t)(pix0 + j) * 256 + tid];
    __syncthreads();
    __shared__ float rs[32][9], rq[32][9];
    __shared__ float muA[32], rsA[32];
    int p = tid >> 3, q = tid & 7;
    float s = 0.f, sq = 0.f;
    for (int c = q * 32; c < q * 32 + 32; ++c) { float v = zf[p][c]; s += v; sq += v * v; }
    rs[p][q] = s; rq[p][q] = sq; __syncthreads();
    if (q == 0) {
        float S = 0.f, Q = 0.f;
#pragma unroll
        for (int t = 0; t < 8; ++t) { S += rs[p][t]; Q += rq[p][t]; }
        float mu = S / 256.f;
        float var = Q / 256.f - mu * mu;
        muA[p] = mu; rsA[p] = rsqrtf(var + EPSV);
    }
    __syncthreads();
    int cg = tid >> 5, xi = tid & 31;
    for (int cc = 0; cc < 32; ++cc) {
        int c = cc * 8 + cg;
        float v = (zf[xi][c] - muA[xi]) * rsA[xi] * g[c] + b[c];
        size_t gi = ((size_t)(n * 256 + c) * 128 + y) * 128 + x0 + xi;
        outp[gi] = xin[gi] + v;
    }
}

extern "C" void kernel_launch(void* const* d_in, const int* in_sizes, int n_in,
                              void* d_out, int out_size, void* d_ws, size_t ws_size,
                              hipStream_t stream) {
    (void)in_sizes; (void)n_in; (void)out_size; (void)ws_size;
    const float* x1     = (const float*)d_in[0];
    const float* x2     = (const float*)d_in[1];
    const float* qk_w   = (const float*)d_in[2];
    const float* qk_g   = (const float*)d_in[3];
    const float* qk_b   = (const float*)d_in[4];
    const float* qk_m   = (const float*)d_in[5];
    const float* qk_v   = (const float*)d_in[6];
    const float* v_w    = (const float*)d_in[7];
    const float* v_g    = (const float*)d_in[8];
    const float* v_b    = (const float*)d_in[9];
    const float* v_m    = (const float*)d_in[10];
    const float* v_v    = (const float*)d_in[11];
    const float* ln1_g  = (const float*)d_in[12];
    const float* ln1_b  = (const float*)d_in[13];
    const float* ln2_g  = (const float*)d_in[14];
    const float* ln2_b  = (const float*)d_in[15];
    const float* merge_w = (const float*)d_in[16];
    const float* mlp_w1 = (const float*)d_in[17];
    const float* mlp_w2 = (const float*)d_in[18];

    float* ws      = (float*)d_ws;
    float* pooled  = ws + OFF_P;
    float* qkvbuf  = ws + OFF_Q;     // q,k,v1,v2 contiguous, 1,048,576 apart
    float* kbuf    = ws + OFF_K;
    float* v1buf   = ws + OFF_V1;
    float* v2buf   = ws + OFF_V2;
    float* m1buf   = ws + OFF_M1;
    float* m2buf   = ws + OFF_M2;
    float* mgbuf   = ws + OFF_MG;
    float* regA    = ws + OFF_A;     // scores -> z -> o (stream-ordered reuse)
    unsigned short* hid = (unsigned short*)(ws + OFF_HID);
    float* outp    = (float*)d_out;

    hipMemsetAsync(m2buf, 0, 1048576 * sizeof(float), stream);

    pool_kernel<<<8192, 256, 0, stream>>>(x1, x2, pooled);
    lnc_kernel<<<8192, 256, 0, stream>>>(pooled, ln1_g, ln1_b);
    dwbn_kernel<<<dim3(4096, 4), 256, 0, stream>>>(pooled,
        qk_w, qk_g, qk_b, qk_m, qk_v, v_w, v_g, v_b, v_m, v_v, qkvbuf);
    qk_kernel<<<dim3(32, 32, 4), 256, 0, stream>>>(qkvbuf, kbuf, regA);
    m1_kernel<<<dim3(32, 8, 4), 256, 0, stream>>>(regA, v2buf, m1buf);
    m2_kernel<<<dim3(32, 4, 4), 256, 0, stream>>>(regA, v1buf, m2buf);

    for (int br = 0; br < 2; ++br) {
        const float* xin = br ? x2 : x1;
        const float* mm  = br ? m2buf : m1buf;
        merge_kernel<<<512, 256, 0, stream>>>(mm, merge_w, mgbuf);
        zbuild_kernel<<<2048, 256, 0, stream>>>(xin, mgbuf, regA);
        gemm_kernel<<<dim3(1024, 8), 256, 0, stream>>>(regA, nullptr, mlp_w1, nullptr, hid, 512, 1);
        gemm_kernel<<<dim3(1024, 4), 256, 0, stream>>>(nullptr, hid, mlp_w2, regA, nullptr, 256, 0);
        final_kernel<<<dim3(4, 128, 4), 256, 0, stream>>>(regA, xin, ln2_g, ln2_b,
                                                          outp + (size_t)br * 16777216);
    }
}

// Round 2
// 1142.915 us; speedup vs baseline: 2.1098x; 2.1098x over previous
//
#include <hip/hip_runtime.h>
#include <hip/hip_bf16.h>

// Problem constants
#define NB 4
#define NC 256
#define NH_ 8
#define LPOOL 1024          // 32*32
constexpr float EPSV = 1e-5f;

typedef unsigned short ushort_t;
typedef __attribute__((ext_vector_type(8))) short bf16x8;
typedef __attribute__((ext_vector_type(4))) float f32x4;

// workspace offsets (in floats)
#define OFF_P   0u                  // pooled/normed: 2*4*256*1024 = 2,097,152
#define OFF_Q   2097152u            // 1,048,576 each
#define OFF_K   3145728u
#define OFF_V1  4194304u
#define OFF_V2  5242880u
#define OFF_M1  6291456u
#define OFF_M2  7340032u
#define OFF_MG  8388608u
#define OFF_A   9437184u            // RegionA: scores (33.5M f) -> z bf16 (16.7M f-slots) -> o f32 (16.7M f)
#define OFF_W1B 26214400u           // bf16 w1: 262144 ushorts = 131072 float slots (in dead scores tail)
#define OFF_W2B 26345472u           // bf16 w2: 131072 ushorts =  65536 float slots
#define OFF_HID 42991616u           // hidden bf16: 33,554,432 ushorts

__device__ __forceinline__ float bf16_to_f(unsigned short u) {
    union { unsigned int ui; float f; } t; t.ui = ((unsigned int)u) << 16; return t.f;
}
__device__ __forceinline__ unsigned short f_to_bf16(float f) {
    union { float f; unsigned int u; } t; t.f = f;
    unsigned int u = t.u;
    u += 0x7fffu + ((u >> 16) & 1u);
    return (unsigned short)(u >> 16);
}

// ---------------- maxpool 4x4 (both branches) ----------------
__global__ __launch_bounds__(256) void pool_kernel(const float* __restrict__ x1,
                                                   const float* __restrict__ x2,
                                                   float* __restrict__ pooled) {
    int idx = blockIdx.x * 256 + threadIdx.x;           // 2^21 total
    int j = idx & 31, i = (idx >> 5) & 31, c = (idx >> 10) & 255, n = (idx >> 18) & 3, br = idx >> 20;
    const float* xp = br ? x2 : x1;
    const float* base = xp + (((size_t)(n * 256 + c) * 128 + i * 4) * 128 + j * 4);
    float m = -3.4e38f;
#pragma unroll
    for (int r = 0; r < 4; ++r) {
        float4 v = *(const float4*)(base + r * 128);
        m = fmaxf(m, fmaxf(fmaxf(v.x, v.y), fmaxf(v.z, v.w)));
    }
    pooled[(size_t)br * 1048576 + (size_t)(n * 256 + c) * 1024 + i * 32 + j] = m;
}

// ---------------- LayerNorm over channel dim, in place ----------------
__global__ __launch_bounds__(256) void lnc_kernel(float* __restrict__ p,
                                                  const float* __restrict__ g,
                                                  const float* __restrict__ b) {
    int bid = blockIdx.x;                                // (br,n,l)
    int l = bid & 1023, n = (bid >> 10) & 3, br = bid >> 12;
    int c = threadIdx.x;
    size_t idx = (size_t)br * 1048576 + (size_t)(n * 256 + c) * 1024 + l;
    float v = p[idx];
    __shared__ float red[256];
    red[c] = v; __syncthreads();
    for (int off = 128; off > 0; off >>= 1) { if (c < off) red[c] += red[c + off]; __syncthreads(); }
    float mean = red[0] / 256.f;
    __syncthreads();
    float d = v - mean;
    red[c] = d * d; __syncthreads();
    for (int off = 128; off > 0; off >>= 1) { if (c < off) red[c] += red[c + off]; __syncthreads(); }
    float var = red[0] / 256.f;
    float rstd = rsqrtf(var + EPSV);
    p[idx] = (v - mean) * rstd * g[c] + b[c];
}

// ---------------- depthwise 3x3 conv + BN; writes heads layout [n][l][c] ----------------
__global__ __launch_bounds__(256) void dwbn_kernel(const float* __restrict__ p,
    const float* __restrict__ qkw, const float* __restrict__ qkg, const float* __restrict__ qkb,
    const float* __restrict__ qkm, const float* __restrict__ qkv,
    const float* __restrict__ vw, const float* __restrict__ vg, const float* __restrict__ vb,
    const float* __restrict__ vm, const float* __restrict__ vv,
    float* __restrict__ qkvbuf) {
    int which = blockIdx.y;                        // 0:q(p1,qk) 1:k(p2,qk) 2:v1(p1,v) 3:v2(p2,v)
    int flat = blockIdx.x * 256 + threadIdx.x;     // 2^20
    int l = flat & 1023, c = (flat >> 10) & 255, n = flat >> 18;
    int br = which & 1;
    const float* w  = (which < 2) ? qkw : vw;
    const float* g  = (which < 2) ? qkg : vg;
    const float* bb = (which < 2) ? qkb : vb;
    const float* rm = (which < 2) ? qkm : vm;
    const float* rv = (which < 2) ? qkv : vv;
    int i = l >> 5, j = l & 31;
    const float* pin = p + (size_t)br * 1048576 + (size_t)(n * 256 + c) * 1024;
    float acc = 0.f;
#pragma unroll
    for (int ky = -1; ky <= 1; ++ky) {
        int yy = i + ky;
        if ((unsigned)yy < 32u) {
#pragma unroll
            for (int kx = -1; kx <= 1; ++kx) {
                int xx = j + kx;
                if ((unsigned)xx < 32u)
                    acc += pin[yy * 32 + xx] * w[c * 9 + (ky + 1) * 3 + (kx + 1)];
            }
        }
    }
    float sc = g[c] * rsqrtf(rv[c] + EPSV);
    qkvbuf[(size_t)which * 1048576 + (size_t)(n * 1024 + l) * 256 + c] = sc * (acc - rm[c]) + bb[c];
}

// ---------------- scores[n][h][l][s] = t * sum_d q*k ----------------
__global__ __launch_bounds__(256) void qk_kernel(const float* __restrict__ q,
                                                 const float* __restrict__ k,
                                                 float* __restrict__ scores) {
    int lt = blockIdx.x, st = blockIdx.y, n = blockIdx.z;
    int l0 = lt * 32, s0 = st * 32;
    int tid = threadIdx.x;
    const float tsc = 0.17677669529663687f;   // 1/sqrt(32)
    __shared__ float Qs[128][34];
    __shared__ float Ks[128][34];
    float acc[2][2][8];
#pragma unroll
    for (int i = 0; i < 2; ++i)
#pragma unroll
        for (int j = 0; j < 2; ++j)
#pragma unroll
            for (int h = 0; h < 8; ++h) acc[i][j][h] = 0.f;
    int ty = tid >> 4, tx = tid & 15;
#pragma unroll
    for (int ch = 0; ch < 2; ++ch) {
        int cbase = ch * 128;
        for (int it = 0; it < 16; ++it) {
            int li = it * 2 + (tid >> 7);
            int cl = tid & 127;
            Qs[cl][li] = tsc * q[(size_t)(n * 1024 + l0 + li) * 256 + cbase + cl];
            Ks[cl][li] = k[(size_t)(n * 1024 + s0 + li) * 256 + cbase + cl];
        }
        __syncthreads();
#pragma unroll
        for (int h8 = 0; h8 < 4; ++h8) {
            for (int c2 = 0; c2 < 32; ++c2) {
                int cl = h8 * 32 + c2;
                float2 qv = *(const float2*)&Qs[cl][ty * 2];
                float2 kv = *(const float2*)&Ks[cl][tx * 2];
                acc[0][0][ch * 4 + h8] += qv.x * kv.x;
                acc[0][1][ch * 4 + h8] += qv.x * kv.y;
                acc[1][0][ch * 4 + h8] += qv.y * kv.x;
                acc[1][1][ch * 4 + h8] += qv.y * kv.y;
            }
        }
        __syncthreads();
    }
#pragma unroll
    for (int h = 0; h < 8; ++h)
#pragma unroll
        for (int i = 0; i < 2; ++i) {
            size_t o = ((size_t)(n * 8 + h) * 1024 + l0 + ty * 2 + i) * 1024 + s0 + tx * 2;
            *(float2*)&scores[o] = make_float2(acc[i][0][h], acc[i][1][h]);
        }
}

// ---------------- m1[n,l,h,d] = sum_s softmax_s(sc)[l,s] * v2[s, h*32+d] ----------------
__global__ __launch_bounds__(256) void m1_kernel(const float* __restrict__ scores,
                                                 const float* __restrict__ v2,
                                                 float* __restrict__ m1out) {
    int lt = blockIdx.x, h = blockIdx.y, n = blockIdx.z;
    int l0 = lt * 32, tid = threadIdx.x;
    const float* sb = scores + (size_t)(n * 8 + h) * 1024 * 1024;
    __shared__ float red[32][9];
    __shared__ float rowmax[32], rowinv[32];
    __shared__ float wls[32][36];   // [ss][l]
    __shared__ float v2s[32][36];   // [ss][d]
    int li = tid >> 3, sg = tid & 7;
    float pm = -3.4e38f;
    for (int s = sg; s < 1024; s += 8) pm = fmaxf(pm, sb[(size_t)(l0 + li) * 1024 + s]);
    red[li][sg] = pm; __syncthreads();
    if (sg == 0) { float m = red[li][0]; for (int t = 1; t < 8; ++t) m = fmaxf(m, red[li][t]); rowmax[li] = m; }
    __syncthreads();
    float rmx = rowmax[li];
    float ps = 0.f;
    for (int s = sg; s < 1024; s += 8) ps += expf(sb[(size_t)(l0 + li) * 1024 + s] - rmx);
    red[li][sg] = ps; __syncthreads();
    if (sg == 0) { float s = 0; for (int t = 0; t < 8; ++t) s += red[li][t]; rowinv[li] = 1.f / s; }
    __syncthreads();
    float rinv = rowinv[li];
    int lg = tid >> 5, d = tid & 31;
    float a0 = 0, a1 = 0, a2 = 0, a3 = 0;
    int ssi = tid >> 3, dg = tid & 7;
    for (int s0c = 0; s0c < 1024; s0c += 32) {
        float4 vvv = *(const float4*)&v2[(size_t)(n * 1024 + s0c + ssi) * 256 + h * 32 + dg * 4];
        *(float4*)&v2s[ssi][dg * 4] = vvv;
        for (int ss = sg; ss < 32; ss += 8) {
            float v = sb[(size_t)(l0 + li) * 1024 + s0c + ss];
            wls[ss][li] = expf(v - rmx) * rinv;
        }
        __syncthreads();
#pragma unroll 8
        for (int ss = 0; ss < 32; ++ss) {
            float v2v = v2s[ss][d];
            float4 w4 = *(const float4*)&wls[ss][lg * 4];
            a0 += w4.x * v2v; a1 += w4.y * v2v; a2 += w4.z * v2v; a3 += w4.w * v2v;
        }
        __syncthreads();
    }
    size_t ob = (size_t)(n * 1024 + l0 + lg * 4) * 256 + h * 32 + d;
    m1out[ob] = a0; m1out[ob + 256] = a1; m1out[ob + 512] = a2; m1out[ob + 768] = a3;
}

// ---------------- m2[n,s,h,d] = sum_l softmax_h(sc)[l,s,h] * v1[l, h*32+d] ----------------
__global__ __launch_bounds__(256) void m2_kernel(const float* __restrict__ scores,
                                                 const float* __restrict__ v1,
                                                 float* __restrict__ m2out) {
    int st = blockIdx.x, lc = blockIdx.y, n = blockIdx.z;
    int s0 = st * 32, tid = threadIdx.x;
    int h = tid >> 5, si = tid & 31;
    __shared__ float scs[8][36];
    __shared__ float es[8][36];
    float acc[32];
#pragma unroll
    for (int i = 0; i < 32; ++i) acc[i] = 0.f;
    int lend = lc * 256 + 256;
    for (int l = lc * 256; l < lend; ++l) {
        float sc = scores[((size_t)(n * 8 + h) * 1024 + l) * 1024 + s0 + si];
        scs[h][si] = sc;
        __syncthreads();
        float mx = scs[0][si];
#pragma unroll
        for (int hh = 1; hh < 8; ++hh) mx = fmaxf(mx, scs[hh][si]);
        float e = expf(sc - mx);
        es[h][si] = e;
        __syncthreads();
        float ssum = es[0][si];
#pragma unroll
        for (int hh = 1; hh < 8; ++hh) ssum += es[hh][si];
        scs[h][si] = e / ssum;
        __syncthreads();
        float v1v = v1[(size_t)(n * 1024 + l) * 256 + tid];
#pragma unroll
        for (int ss = 0; ss < 32; ss += 4) {
            float4 w4 = *(const float4*)&scs[h][ss];
            acc[ss] += w4.x * v1v; acc[ss + 1] += w4.y * v1v;
            acc[ss + 2] += w4.z * v1v; acc[ss + 3] += w4.w * v1v;
        }
        __syncthreads();
    }
#pragma unroll
    for (int ss = 0; ss < 32; ++ss)
        atomicAdd(&m2out[(size_t)(n * 1024 + s0 + ss) * 256 + tid], acc[ss]);
}

// ---------------- merged[n,l,c] = sum_c' m[n,l,c'] * merge_w[c,c'] ----------------
__global__ __launch_bounds__(256) void merge_kernel(const float* __restrict__ m,
                                                    const float* __restrict__ mw,
                                                    float* __restrict__ merged) {
    int bid = blockIdx.x;
    int n = bid >> 7, lt = bid & 127;
    int l0 = lt * 8, tid = threadIdx.x;
    __shared__ float ms[8][260];
#pragma unroll
    for (int r = 0; r < 8; ++r) ms[r][tid] = m[(size_t)(n * 1024 + l0 + r) * 256 + tid];
    __syncthreads();
    float acc[8];
#pragma unroll
    for (int r = 0; r < 8; ++r) acc[r] = 0.f;
    const float4* wrow = (const float4*)(mw + (size_t)tid * 256);
    for (int c4 = 0; c4 < 64; ++c4) {
        float4 w4 = wrow[c4];
#pragma unroll
        for (int r = 0; r < 8; ++r) {
            float4 m4 = *(const float4*)&ms[r][c4 * 4];
            acc[r] += w4.x * m4.x + w4.y * m4.y + w4.z * m4.z + w4.w * m4.w;
        }
    }
#pragma unroll
    for (int r = 0; r < 8; ++r)
        merged[(size_t)(n * 1024 + l0 + r) * 256 + tid] = acc[r];
}

// ---------------- z[pix][512] (bf16) = concat(x NHWC, bilinear-up(merged)) ----------------
__global__ __launch_bounds__(256) void zbuild_kernel(const float* __restrict__ x,
                                                     const float* __restrict__ merged,
                                                     ushort_t* __restrict__ z) {
    int pix0 = blockIdx.x * 32;
    int n = pix0 >> 14, y = (pix0 >> 7) & 127, x0 = pix0 & 127;
    int tid = threadIdx.x;
    int ci = tid >> 5, xi = tid & 31;
    __shared__ float xs[256][33];
    for (int cc = 0; cc < 32; ++cc) {
        int c = cc * 8 + ci;
        xs[c][xi] = x[((size_t)(n * 256 + c) * 128 + y) * 128 + x0 + xi];
    }
    __syncthreads();
    float iy = y * 0.25f - 0.375f;
    int y0i = (int)floorf(iy);
    float fy = iy - (float)y0i;
    int y0c = max(y0i, 0), y1c = min(y0i + 1, 31);
    const float* mb = merged + (size_t)n * 1024 * 256;
    for (int xj = 0; xj < 32; ++xj) {
        size_t zb = (size_t)(pix0 + xj) * 512;
        z[zb + tid] = f_to_bf16(xs[tid][xj]);
        int xx = x0 + xj;
        float ix = xx * 0.25f - 0.375f;
        int x0i = (int)floorf(ix);
        float fx = ix - (float)x0i;
        int x0cc = max(x0i, 0), x1cc = min(x0i + 1, 31);
        float v00 = mb[(size_t)(y0c * 32 + x0cc) * 256 + tid];
        float v01 = mb[(size_t)(y0c * 32 + x1cc) * 256 + tid];
        float v10 = mb[(size_t)(y1c * 32 + x0cc) * 256 + tid];
        float v11 = mb[(size_t)(y1c * 32 + x1cc) * 256 + tid];
        float v = (1.f - fy) * ((1.f - fx) * v00 + fx * v01) + fy * ((1.f - fx) * v10 + fx * v11);
        z[zb + 256 + tid] = f_to_bf16(v);
    }
}

// ---------------- fp32 -> bf16 weight conversion ----------------
__global__ __launch_bounds__(256) void cvt_kernel(const float* __restrict__ in,
                                                  ushort_t* __restrict__ out, int n) {
    int i = blockIdx.x * 256 + threadIdx.x;
    if (i < n) out[i] = f_to_bf16(in[i]);
}

// ---------------- MFMA bf16 GEMM: C[M,N] = act(A[M,512] @ B[N,512]^T) ----------------
// 128x128 tile, 4 waves (2x2), each wave 4x4 subtiles of 16x16x32 MFMA.
__global__ __launch_bounds__(256) void mfma_gemm(const ushort_t* __restrict__ A,
                                                 const ushort_t* __restrict__ B,
                                                 float* __restrict__ Of,
                                                 ushort_t* __restrict__ Oh,
                                                 int N, int relu) {
    const int K = 512;
    int m0 = blockIdx.x * 128, n0 = blockIdx.y * 128;
    int tid = threadIdx.x;
    __shared__ ushort_t Al[128 * 32];
    __shared__ ushort_t Bl[128 * 32];
    int lane = tid & 63;
    int wv = tid >> 6;
    int wm = wv >> 1, wn = wv & 1;          // 2x2 wave grid -> 64x64 per wave
    int ml = lane & 15, quad = lane >> 4;
    f32x4 acc[4][4];
#pragma unroll
    for (int i = 0; i < 4; ++i)
#pragma unroll
        for (int j = 0; j < 4; ++j) acc[i][j] = (f32x4)(0.f);

    for (int k0 = 0; k0 < K; k0 += 32) {
        // stage A,B tiles: 128 rows x 32 k (bf16) each = 16 KB total, width-16 global_load_lds
#pragma unroll
        for (int c = 0; c < 2; ++c) {
            int g = c * 256 + tid;
            int row = g >> 2, seg = g & 3;
            const ushort_t* ga = A + (size_t)(m0 + row) * K + k0 + seg * 8;
            __builtin_amdgcn_global_load_lds((const __attribute__((address_space(1))) void*)ga,
                                             (__attribute__((address_space(3))) void*)&Al[g * 8], 16, 0, 0);
            const ushort_t* gb = B + (size_t)(n0 + row) * K + k0 + seg * 8;
            __builtin_amdgcn_global_load_lds((const __attribute__((address_space(1))) void*)gb,
                                             (__attribute__((address_space(3))) void*)&Bl[g * 8], 16, 0, 0);
        }
        __syncthreads();
        bf16x8 af[4], bfr[4];
#pragma unroll
        for (int mt = 0; mt < 4; ++mt)
            af[mt] = *(const bf16x8*)&Al[(wm * 64 + mt * 16 + ml) * 32 + quad * 8];
#pragma unroll
        for (int nt = 0; nt < 4; ++nt)
            bfr[nt] = *(const bf16x8*)&Bl[(wn * 64 + nt * 16 + ml) * 32 + quad * 8];
#pragma unroll
        for (int mt = 0; mt < 4; ++mt)
#pragma unroll
            for (int nt = 0; nt < 4; ++nt)
                acc[mt][nt] = __builtin_amdgcn_mfma_f32_16x16x32_bf16(af[mt], bfr[nt], acc[mt][nt], 0, 0, 0);
        __syncthreads();
    }
    // epilogue: D row = quad*4+reg (within 16), col = ml
#pragma unroll
    for (int mt = 0; mt < 4; ++mt) {
#pragma unroll
        for (int nt = 0; nt < 4; ++nt) {
            int col = n0 + wn * 64 + nt * 16 + ml;
#pragma unroll
            for (int r = 0; r < 4; ++r) {
                int row = m0 + wm * 64 + mt * 16 + quad * 4 + r;
                float v = acc[mt][nt][r];
                if (relu) v = fmaxf(v, 0.f);
                if (Oh) Oh[(size_t)row * N + col] = f_to_bf16(v);
                else    Of[(size_t)row * N + col] = v;
            }
        }
    }
}

// ---------------- LN over channels + residual + NCHW write ----------------
__global__ __launch_bounds__(256) void final_kernel(const float* __restrict__ o,
                                                    const float* __restrict__ xin,
                                                    const float* __restrict__ g,
                                                    const float* __restrict__ b,
                                                    float* __restrict__ outp) {
    int xg = blockIdx.x, y = blockIdx.y, n = blockIdx.z;
    int x0 = xg * 32;
    int pix0 = (n * 128 + y) * 128 + x0;
    int tid = threadIdx.x;
    __shared__ float zf[32][257];
    for (int j = 0; j < 32; ++j) zf[j][tid] = o[(size_t)(pix0 + j) * 256 + tid];
    __syncthreads();
    __shared__ float rs[32][9], rq[32][9];
    __shared__ float muA[32], rsA[32];
    int p = tid >> 3, q = tid & 7;
    float s = 0.f, sq = 0.f;
    for (int c = q * 32; c < q * 32 + 32; ++c) { float v = zf[p][c]; s += v; sq += v * v; }
    rs[p][q] = s; rq[p][q] = sq; __syncthreads();
    if (q == 0) {
        float S = 0.f, Q = 0.f;
#pragma unroll
        for (int t = 0; t < 8; ++t) { S += rs[p][t]; Q += rq[p][t]; }
        float mu = S / 256.f;
        float var = Q / 256.f - mu * mu;
        muA[p] = mu; rsA[p] = rsqrtf(var + EPSV);
    }
    __syncthreads();
    int cg = tid >> 5, xi = tid & 31;
    for (int cc = 0; cc < 32; ++cc) {
        int c = cc * 8 + cg;
        float v = (zf[xi][c] - muA[xi]) * rsA[xi] * g[c] + b[c];
        size_t gi = ((size_t)(n * 256 + c) * 128 + y) * 128 + x0 + xi;
        outp[gi] = xin[gi] + v;
    }
}

extern "C" void kernel_launch(void* const* d_in, const int* in_sizes, int n_in,
                              void* d_out, int out_size, void* d_ws, size_t ws_size,
                              hipStream_t stream) {
    (void)in_sizes; (void)n_in; (void)out_size; (void)ws_size;
    const float* x1     = (const float*)d_in[0];
    const float* x2     = (const float*)d_in[1];
    const float* qk_w   = (const float*)d_in[2];
    const float* qk_g   = (const float*)d_in[3];
    const float* qk_b   = (const float*)d_in[4];
    const float* qk_m   = (const float*)d_in[5];
    const float* qk_v   = (const float*)d_in[6];
    const float* v_w    = (const float*)d_in[7];
    const float* v_g    = (const float*)d_in[8];
    const float* v_b    = (const float*)d_in[9];
    const float* v_m    = (const float*)d_in[10];
    const float* v_v    = (const float*)d_in[11];
    const float* ln1_g  = (const float*)d_in[12];
    const float* ln1_b  = (const float*)d_in[13];
    const float* ln2_g  = (const float*)d_in[14];
    const float* ln2_b  = (const float*)d_in[15];
    const float* merge_w = (const float*)d_in[16];
    const float* mlp_w1 = (const float*)d_in[17];
    const float* mlp_w2 = (const float*)d_in[18];

    float* ws      = (float*)d_ws;
    float* pooled  = ws + OFF_P;
    float* qkvbuf  = ws + OFF_Q;     // q,k,v1,v2 contiguous, 1,048,576 apart
    float* kbuf    = ws + OFF_K;
    float* v1buf   = ws + OFF_V1;
    float* v2buf   = ws + OFF_V2;
    float* m1buf   = ws + OFF_M1;
    float* m2buf   = ws + OFF_M2;
    float* mgbuf   = ws + OFF_MG;
    float* regA    = ws + OFF_A;     // scores -> z(bf16) -> o (stream-ordered reuse)
    ushort_t* zb16 = (ushort_t*)(ws + OFF_A);
    ushort_t* w1b  = (ushort_t*)(ws + OFF_W1B);
    ushort_t* w2b  = (ushort_t*)(ws + OFF_W2B);
    ushort_t* hid  = (ushort_t*)(ws + OFF_HID);
    float* outp    = (float*)d_out;

    hipMemsetAsync(m2buf, 0, 1048576 * sizeof(float), stream);

    pool_kernel<<<8192, 256, 0, stream>>>(x1, x2, pooled);
    lnc_kernel<<<8192, 256, 0, stream>>>(pooled, ln1_g, ln1_b);
    dwbn_kernel<<<dim3(4096, 4), 256, 0, stream>>>(pooled,
        qk_w, qk_g, qk_b, qk_m, qk_v, v_w, v_g, v_b, v_m, v_v, qkvbuf);
    qk_kernel<<<dim3(32, 32, 4), 256, 0, stream>>>(qkvbuf, kbuf, regA);
    m1_kernel<<<dim3(32, 8, 4), 256, 0, stream>>>(regA, v2buf, m1buf);
    m2_kernel<<<dim3(32, 4, 4), 256, 0, stream>>>(regA, v1buf, m2buf);

    // weight conversion (after m2: w1b/w2b live in the dead scores tail)
    cvt_kernel<<<1024, 256, 0, stream>>>(mlp_w1, w1b, 262144);
    cvt_kernel<<<512, 256, 0, stream>>>(mlp_w2, w2b, 131072);

    for (int br = 0; br < 2; ++br) {
        const float* xin = br ? x2 : x1;
        const float* mm  = br ? m2buf : m1buf;
        merge_kernel<<<512, 256, 0, stream>>>(mm, merge_w, mgbuf);
        zbuild_kernel<<<2048, 256, 0, stream>>>(xin, mgbuf, zb16);
        mfma_gemm<<<dim3(512, 4), 256, 0, stream>>>(zb16, w1b, nullptr, hid, 512, 1);
        mfma_gemm<<<dim3(512, 2), 256, 0, stream>>>(hid, w2b, regA, nullptr, 256, 0);
        final_kernel<<<dim3(4, 128, 4), 256, 0, stream>>>(regA, xin, ln2_g, ln2_b,
                                                          outp + (size_t)br * 16777216);
    }
}

// Round 3
// 925.596 us; speedup vs baseline: 2.6052x; 1.2348x over previous
//
#include <hip/hip_runtime.h>
#include <hip/hip_bf16.h>

// Problem constants
#define NB 4
#define NC 256
#define NH_ 8
#define LPOOL 1024          // 32*32
constexpr float EPSV = 1e-5f;

typedef unsigned short ushort_t;
typedef __attribute__((ext_vector_type(8))) short bf16x8;
typedef __attribute__((ext_vector_type(4))) float f32x4;

// workspace offsets (in floats)
#define OFF_P   0u                  // pooled/normed: 2*4*256*1024 = 2,097,152 (reused for bf16 q/k after dwbn)
#define OFF_Q   2097152u            // 1,048,576 each
#define OFF_K   3145728u
#define OFF_V1  4194304u
#define OFF_V2  5242880u
#define OFF_M1  6291456u
#define OFF_M2  7340032u
#define OFF_MG  8388608u
#define OFF_A   9437184u            // RegionA: scores (33.5M f) -> z bf16 (16.7M f-slots) -> o f32 (16.7M f)
#define OFF_W1B 26214400u           // bf16 w1: 262144 ushorts = 131072 float slots (in dead scores tail)
#define OFF_W2B 26345472u           // bf16 w2: 131072 ushorts =  65536 float slots
#define OFF_HID 42991616u           // hidden bf16: 33,554,432 ushorts

__device__ __forceinline__ float bf16_to_f(unsigned short u) {
    union { unsigned int ui; float f; } t; t.ui = ((unsigned int)u) << 16; return t.f;
}
__device__ __forceinline__ unsigned short f_to_bf16(float f) {
    union { float f; unsigned int u; } t; t.f = f;
    unsigned int u = t.u;
    u += 0x7fffu + ((u >> 16) & 1u);
    return (unsigned short)(u >> 16);
}

// ---------------- maxpool 4x4 (both branches) ----------------
__global__ __launch_bounds__(256) void pool_kernel(const float* __restrict__ x1,
                                                   const float* __restrict__ x2,
                                                   float* __restrict__ pooled) {
    int idx = blockIdx.x * 256 + threadIdx.x;           // 2^21 total
    int j = idx & 31, i = (idx >> 5) & 31, c = (idx >> 10) & 255, n = (idx >> 18) & 3, br = idx >> 20;
    const float* xp = br ? x2 : x1;
    const float* base = xp + (((size_t)(n * 256 + c) * 128 + i * 4) * 128 + j * 4);
    float m = -3.4e38f;
#pragma unroll
    for (int r = 0; r < 4; ++r) {
        float4 v = *(const float4*)(base + r * 128);
        m = fmaxf(m, fmaxf(fmaxf(v.x, v.y), fmaxf(v.z, v.w)));
    }
    pooled[(size_t)br * 1048576 + (size_t)(n * 256 + c) * 1024 + i * 32 + j] = m;
}

// ---------------- LayerNorm over channel dim, in place ----------------
__global__ __launch_bounds__(256) void lnc_kernel(float* __restrict__ p,
                                                  const float* __restrict__ g,
                                                  const float* __restrict__ b) {
    int bid = blockIdx.x;                                // (br,n,l)
    int l = bid & 1023, n = (bid >> 10) & 3, br = bid >> 12;
    int c = threadIdx.x;
    size_t idx = (size_t)br * 1048576 + (size_t)(n * 256 + c) * 1024 + l;
    float v = p[idx];
    __shared__ float red[256];
    red[c] = v; __syncthreads();
    for (int off = 128; off > 0; off >>= 1) { if (c < off) red[c] += red[c + off]; __syncthreads(); }
    float mean = red[0] / 256.f;
    __syncthreads();
    float d = v - mean;
    red[c] = d * d; __syncthreads();
    for (int off = 128; off > 0; off >>= 1) { if (c < off) red[c] += red[c + off]; __syncthreads(); }
    float var = red[0] / 256.f;
    float rstd = rsqrtf(var + EPSV);
    p[idx] = (v - mean) * rstd * g[c] + b[c];
}

// ---------------- depthwise 3x3 conv + BN; writes heads layout [n][l][c] ----------------
__global__ __launch_bounds__(256) void dwbn_kernel(const float* __restrict__ p,
    const float* __restrict__ qkw, const float* __restrict__ qkg, const float* __restrict__ qkb,
    const float* __restrict__ qkm, const float* __restrict__ qkv,
    const float* __restrict__ vw, const float* __restrict__ vg, const float* __restrict__ vb,
    const float* __restrict__ vm, const float* __restrict__ vv,
    float* __restrict__ qkvbuf) {
    int which = blockIdx.y;                        // 0:q(p1,qk) 1:k(p2,qk) 2:v1(p1,v) 3:v2(p2,v)
    int flat = blockIdx.x * 256 + threadIdx.x;     // 2^20
    int l = flat & 1023, c = (flat >> 10) & 255, n = flat >> 18;
    int br = which & 1;
    const float* w  = (which < 2) ? qkw : vw;
    const float* g  = (which < 2) ? qkg : vg;
    const float* bb = (which < 2) ? qkb : vb;
    const float* rm = (which < 2) ? qkm : vm;
    const float* rv = (which < 2) ? qkv : vv;
    int i = l >> 5, j = l & 31;
    const float* pin = p + (size_t)br * 1048576 + (size_t)(n * 256 + c) * 1024;
    float acc = 0.f;
#pragma unroll
    for (int ky = -1; ky <= 1; ++ky) {
        int yy = i + ky;
        if ((unsigned)yy < 32u) {
#pragma unroll
            for (int kx = -1; kx <= 1; ++kx) {
                int xx = j + kx;
                if ((unsigned)xx < 32u)
                    acc += pin[yy * 32 + xx] * w[c * 9 + (ky + 1) * 3 + (kx + 1)];
            }
        }
    }
    float sc = g[c] * rsqrtf(rv[c] + EPSV);
    qkvbuf[(size_t)which * 1048576 + (size_t)(n * 1024 + l) * 256 + c] = sc * (acc - rm[c]) + bb[c];
}

// ---------------- fp32 -> bf16 conversion ----------------
__global__ __launch_bounds__(256) void cvt_kernel(const float* __restrict__ in,
                                                  ushort_t* __restrict__ out, int n) {
    int i = blockIdx.x * 256 + threadIdx.x;
    if (i < n) out[i] = f_to_bf16(in[i]);
}

// ---------------- scores[n][h][l][s] = t * Q_h K_h^T via MFMA bf16 ----------------
// grid (8 lt, 8 st, 32 nh); 128x128 tile per block, single K=32 step.
__global__ __launch_bounds__(256) void qk_mfma(const ushort_t* __restrict__ qb,
                                               const ushort_t* __restrict__ kb,
                                               float* __restrict__ scores) {
    int lt = blockIdx.x, st = blockIdx.y;
    int nh = blockIdx.z; int n = nh >> 3, h = nh & 7;
    int l0 = lt * 128, s0 = st * 128;
    __shared__ ushort_t Qs[128 * 32];
    __shared__ ushort_t Ks[128 * 32];
    int tid = threadIdx.x, lane = tid & 63, wv = tid >> 6;
    int wm = wv >> 1, wn = wv & 1;
    int ml = lane & 15, quad = lane >> 4;
#pragma unroll
    for (int c = 0; c < 2; ++c) {
        int g = c * 256 + tid;
        int row = g >> 2, seg = g & 3;
        const ushort_t* ga = qb + (size_t)(n * 1024 + l0 + row) * 256 + h * 32 + seg * 8;
        __builtin_amdgcn_global_load_lds((const __attribute__((address_space(1))) void*)ga,
                                         (__attribute__((address_space(3))) void*)&Qs[row * 32 + seg * 8], 16, 0, 0);
        const ushort_t* gk = kb + (size_t)(n * 1024 + s0 + row) * 256 + h * 32 + seg * 8;
        __builtin_amdgcn_global_load_lds((const __attribute__((address_space(1))) void*)gk,
                                         (__attribute__((address_space(3))) void*)&Ks[row * 32 + seg * 8], 16, 0, 0);
    }
    __syncthreads();
    f32x4 acc[4][4];
#pragma unroll
    for (int i = 0; i < 4; ++i)
#pragma unroll
        for (int j = 0; j < 4; ++j) acc[i][j] = (f32x4)(0.f);
    bf16x8 af[4], bfr[4];
#pragma unroll
    for (int mt = 0; mt < 4; ++mt)
        af[mt] = *(const bf16x8*)&Qs[(wm * 64 + mt * 16 + ml) * 32 + quad * 8];
#pragma unroll
    for (int nt = 0; nt < 4; ++nt)
        bfr[nt] = *(const bf16x8*)&Ks[(wn * 64 + nt * 16 + ml) * 32 + quad * 8];
#pragma unroll
    for (int mt = 0; mt < 4; ++mt)
#pragma unroll
        for (int nt = 0; nt < 4; ++nt)
            acc[mt][nt] = __builtin_amdgcn_mfma_f32_16x16x32_bf16(af[mt], bfr[nt], acc[mt][nt], 0, 0, 0);
    const float tsc = 0.17677669529663687f;   // 1/sqrt(32)
    float* sb = scores + (size_t)nh * 1024 * 1024;
#pragma unroll
    for (int mt = 0; mt < 4; ++mt)
#pragma unroll
        for (int nt = 0; nt < 4; ++nt) {
            int col = s0 + wn * 64 + nt * 16 + ml;
#pragma unroll
            for (int r = 0; r < 4; ++r) {
                int row = l0 + wm * 64 + mt * 16 + quad * 4 + r;
                sb[(size_t)row * 1024 + col] = tsc * acc[mt][nt][r];
            }
        }
}

// ---------------- m1[n,l,h,d] = sum_s softmax_s(sc)[l,s] * v2[s, h*32+d] ----------------
__global__ __launch_bounds__(256) void m1_kernel(const float* __restrict__ scores,
                                                 const float* __restrict__ v2,
                                                 float* __restrict__ m1out) {
    int lt = blockIdx.x, h = blockIdx.y, n = blockIdx.z;
    int l0 = lt * 32, tid = threadIdx.x;
    const float* sb = scores + (size_t)(n * 8 + h) * 1024 * 1024;
    __shared__ float red[32][9];
    __shared__ float rowmax[32], rowinv[32];
    __shared__ float wls[32][36];   // [ss][l]
    __shared__ float v2s[32][36];   // [ss][d]
    int li = tid >> 3, sg = tid & 7;
    float pm = -3.4e38f;
    for (int s = sg; s < 1024; s += 8) pm = fmaxf(pm, sb[(size_t)(l0 + li) * 1024 + s]);
    red[li][sg] = pm; __syncthreads();
    if (sg == 0) { float m = red[li][0]; for (int t = 1; t < 8; ++t) m = fmaxf(m, red[li][t]); rowmax[li] = m; }
    __syncthreads();
    float rmx = rowmax[li];
    float ps = 0.f;
    for (int s = sg; s < 1024; s += 8) ps += expf(sb[(size_t)(l0 + li) * 1024 + s] - rmx);
    red[li][sg] = ps; __syncthreads();
    if (sg == 0) { float s = 0; for (int t = 0; t < 8; ++t) s += red[li][t]; rowinv[li] = 1.f / s; }
    __syncthreads();
    float rinv = rowinv[li];
    int lg = tid >> 5, d = tid & 31;
    float a0 = 0, a1 = 0, a2 = 0, a3 = 0;
    int ssi = tid >> 3, dg = tid & 7;
    for (int s0c = 0; s0c < 1024; s0c += 32) {
        float4 vvv = *(const float4*)&v2[(size_t)(n * 1024 + s0c + ssi) * 256 + h * 32 + dg * 4];
        *(float4*)&v2s[ssi][dg * 4] = vvv;
        for (int ss = sg; ss < 32; ss += 8) {
            float v = sb[(size_t)(l0 + li) * 1024 + s0c + ss];
            wls[ss][li] = expf(v - rmx) * rinv;
        }
        __syncthreads();
#pragma unroll 8
        for (int ss = 0; ss < 32; ++ss) {
            float v2v = v2s[ss][d];
            float4 w4 = *(const float4*)&wls[ss][lg * 4];
            a0 += w4.x * v2v; a1 += w4.y * v2v; a2 += w4.z * v2v; a3 += w4.w * v2v;
        }
        __syncthreads();
    }
    size_t ob = (size_t)(n * 1024 + l0 + lg * 4) * 256 + h * 32 + d;
    m1out[ob] = a0; m1out[ob + 256] = a1; m1out[ob + 512] = a2; m1out[ob + 768] = a3;
}

// ---------------- m2[n,s,h,d] = sum_l softmax_h(sc)[l,s,h] * v1[l, h*32+d] ----------------
// Thread-local h-softmax (8 values per (l,s) in registers); 2 barriers per 8 l.
__global__ __launch_bounds__(256) void m2_kernel(const float* __restrict__ scores,
                                                 const float* __restrict__ v1,
                                                 float* __restrict__ m2out) {
    int st = blockIdx.x;       // 32 tiles of 32 s
    int lc = blockIdx.y;       // 8 chunks of 128 l
    int n  = blockIdx.z;
    int s0 = st * 32, tid = threadIdx.x;
    __shared__ float wls[8][8][32];   // [l_sub][h][s]
    float acc[32];
#pragma unroll
    for (int i = 0; i < 32; ++i) acc[i] = 0.f;
    int lA = tid >> 5, siA = tid & 31;        // phase A: (l_sub, s)
    int hB = tid >> 5;                        // phase B: c = tid, h = tid>>5
    const float* sbase = scores + (size_t)n * 8 * 1024 * 1024;
    int lend = lc * 128 + 128;
    for (int lb = lc * 128; lb < lend; lb += 8) {
        // Phase A: per-thread softmax over h for one (l,s)
        int l = lb + lA;
        float e[8];
        float mx = -3.4e38f;
#pragma unroll
        for (int h = 0; h < 8; ++h) {
            e[h] = sbase[((size_t)h * 1024 + l) * 1024 + s0 + siA];
            mx = fmaxf(mx, e[h]);
        }
        float sum = 0.f;
#pragma unroll
        for (int h = 0; h < 8; ++h) { e[h] = expf(e[h] - mx); sum += e[h]; }
        float inv = 1.f / sum;
#pragma unroll
        for (int h = 0; h < 8; ++h) wls[lA][h][siA] = e[h] * inv;
        __syncthreads();
        // Phase B: accumulate 8 l values
#pragma unroll
        for (int ls = 0; ls < 8; ++ls) {
            float v1v = v1[(size_t)(n * 1024 + lb + ls) * 256 + tid];
#pragma unroll
            for (int s4 = 0; s4 < 8; ++s4) {
                float4 w4 = *(const float4*)&wls[ls][hB][s4 * 4];
                acc[s4 * 4]     += w4.x * v1v;
                acc[s4 * 4 + 1] += w4.y * v1v;
                acc[s4 * 4 + 2] += w4.z * v1v;
                acc[s4 * 4 + 3] += w4.w * v1v;
            }
        }
        __syncthreads();
    }
#pragma unroll
    for (int ss = 0; ss < 32; ++ss)
        atomicAdd(&m2out[(size_t)(n * 1024 + s0 + ss) * 256 + tid], acc[ss]);
}

// ---------------- merged[n,l,c] = sum_c' m[n,l,c'] * merge_w[c,c'] ----------------
__global__ __launch_bounds__(256) void merge_kernel(const float* __restrict__ m,
                                                    const float* __restrict__ mw,
                                                    float* __restrict__ merged) {
    int bid = blockIdx.x;
    int n = bid >> 7, lt = bid & 127;
    int l0 = lt * 8, tid = threadIdx.x;
    __shared__ float ms[8][260];
#pragma unroll
    for (int r = 0; r < 8; ++r) ms[r][tid] = m[(size_t)(n * 1024 + l0 + r) * 256 + tid];
    __syncthreads();
    float acc[8];
#pragma unroll
    for (int r = 0; r < 8; ++r) acc[r] = 0.f;
    const float4* wrow = (const float4*)(mw + (size_t)tid * 256);
    for (int c4 = 0; c4 < 64; ++c4) {
        float4 w4 = wrow[c4];
#pragma unroll
        for (int r = 0; r < 8; ++r) {
            float4 m4 = *(const float4*)&ms[r][c4 * 4];
            acc[r] += w4.x * m4.x + w4.y * m4.y + w4.z * m4.z + w4.w * m4.w;
        }
    }
#pragma unroll
    for (int r = 0; r < 8; ++r)
        merged[(size_t)(n * 1024 + l0 + r) * 256 + tid] = acc[r];
}

// ---------------- z[pix][512] (bf16) = concat(x NHWC, bilinear-up(merged)) ----------------
__global__ __launch_bounds__(256) void zbuild_kernel(const float* __restrict__ x,
                                                     const float* __restrict__ merged,
                                                     ushort_t* __restrict__ z) {
    int pix0 = blockIdx.x * 32;
    int n = pix0 >> 14, y = (pix0 >> 7) & 127, x0 = pix0 & 127;
    int tid = threadIdx.x;
    int ci = tid >> 5, xi = tid & 31;
    __shared__ float xs[256][33];
    for (int cc = 0; cc < 32; ++cc) {
        int c = cc * 8 + ci;
        xs[c][xi] = x[((size_t)(n * 256 + c) * 128 + y) * 128 + x0 + xi];
    }
    __syncthreads();
    float iy = y * 0.25f - 0.375f;
    int y0i = (int)floorf(iy);
    float fy = iy - (float)y0i;
    int y0c = max(y0i, 0), y1c = min(y0i + 1, 31);
    const float* mb = merged + (size_t)n * 1024 * 256;
    for (int xj = 0; xj < 32; ++xj) {
        size_t zb = (size_t)(pix0 + xj) * 512;
        z[zb + tid] = f_to_bf16(xs[tid][xj]);
        int xx = x0 + xj;
        float ix = xx * 0.25f - 0.375f;
        int x0i = (int)floorf(ix);
        float fx = ix - (float)x0i;
        int x0cc = max(x0i, 0), x1cc = min(x0i + 1, 31);
        float v00 = mb[(size_t)(y0c * 32 + x0cc) * 256 + tid];
        float v01 = mb[(size_t)(y0c * 32 + x1cc) * 256 + tid];
        float v10 = mb[(size_t)(y1c * 32 + x0cc) * 256 + tid];
        float v11 = mb[(size_t)(y1c * 32 + x1cc) * 256 + tid];
        float v = (1.f - fy) * ((1.f - fx) * v00 + fx * v01) + fy * ((1.f - fx) * v10 + fx * v11);
        z[zb + 256 + tid] = f_to_bf16(v);
    }
}

// ---------------- MFMA bf16 GEMM: C[M,N] = act(A[M,512] @ B[N,512]^T) ----------------
__global__ __launch_bounds__(256) void mfma_gemm(const ushort_t* __restrict__ A,
                                                 const ushort_t* __restrict__ B,
                                                 float* __restrict__ Of,
                                                 ushort_t* __restrict__ Oh,
                                                 int N, int relu) {
    const int K = 512;
    int m0 = blockIdx.x * 128, n0 = blockIdx.y * 128;
    int tid = threadIdx.x;
    __shared__ ushort_t Al[128 * 32];
    __shared__ ushort_t Bl[128 * 32];
    int lane = tid & 63;
    int wv = tid >> 6;
    int wm = wv >> 1, wn = wv & 1;          // 2x2 wave grid -> 64x64 per wave
    int ml = lane & 15, quad = lane >> 4;
    f32x4 acc[4][4];
#pragma unroll
    for (int i = 0; i < 4; ++i)
#pragma unroll
        for (int j = 0; j < 4; ++j) acc[i][j] = (f32x4)(0.f);

    for (int k0 = 0; k0 < K; k0 += 32) {
#pragma unroll
        for (int c = 0; c < 2; ++c) {
            int g = c * 256 + tid;
            int row = g >> 2, seg = g & 3;
            const ushort_t* ga = A + (size_t)(m0 + row) * K + k0 + seg * 8;
            __builtin_amdgcn_global_load_lds((const __attribute__((address_space(1))) void*)ga,
                                             (__attribute__((address_space(3))) void*)&Al[g * 8], 16, 0, 0);
            const ushort_t* gb = B + (size_t)(n0 + row) * K + k0 + seg * 8;
            __builtin_amdgcn_global_load_lds((const __attribute__((address_space(1))) void*)gb,
                                             (__attribute__((address_space(3))) void*)&Bl[g * 8], 16, 0, 0);
        }
        __syncthreads();
        bf16x8 af[4], bfr[4];
#pragma unroll
        for (int mt = 0; mt < 4; ++mt)
            af[mt] = *(const bf16x8*)&Al[(wm * 64 + mt * 16 + ml) * 32 + quad * 8];
#pragma unroll
        for (int nt = 0; nt < 4; ++nt)
            bfr[nt] = *(const bf16x8*)&Bl[(wn * 64 + nt * 16 + ml) * 32 + quad * 8];
#pragma unroll
        for (int mt = 0; mt < 4; ++mt)
#pragma unroll
            for (int nt = 0; nt < 4; ++nt)
                acc[mt][nt] = __builtin_amdgcn_mfma_f32_16x16x32_bf16(af[mt], bfr[nt], acc[mt][nt], 0, 0, 0);
        __syncthreads();
    }
#pragma unroll
    for (int mt = 0; mt < 4; ++mt) {
#pragma unroll
        for (int nt = 0; nt < 4; ++nt) {
            int col = n0 + wn * 64 + nt * 16 + ml;
#pragma unroll
            for (int r = 0; r < 4; ++r) {
                int row = m0 + wm * 64 + mt * 16 + quad * 4 + r;
                float v = acc[mt][nt][r];
                if (relu) v = fmaxf(v, 0.f);
                if (Oh) Oh[(size_t)row * N + col] = f_to_bf16(v);
                else    Of[(size_t)row * N + col] = v;
            }
        }
    }
}

// ---------------- LN over channels + residual + NCHW write ----------------
__global__ __launch_bounds__(256) void final_kernel(const float* __restrict__ o,
                                                    const float* __restrict__ xin,
                                                    const float* __restrict__ g,
                                                    const float* __restrict__ b,
                                                    float* __restrict__ outp) {
    int xg = blockIdx.x, y = blockIdx.y, n = blockIdx.z;
    int x0 = xg * 32;
    int pix0 = (n * 128 + y) * 128 + x0;
    int tid = threadIdx.x;
    __shared__ float zf[32][257];
    for (int j = 0; j < 32; ++j) zf[j][tid] = o[(size_t)(pix0 + j) * 256 + tid];
    __syncthreads();
    __shared__ float rs[32][9], rq[32][9];
    __shared__ float muA[32], rsA[32];
    int p = tid >> 3, q = tid & 7;
    float s = 0.f, sq = 0.f;
    for (int c = q * 32; c < q * 32 + 32; ++c) { float v = zf[p][c]; s += v; sq += v * v; }
    rs[p][q] = s; rq[p][q] = sq; __syncthreads();
    if (q == 0) {
        float S = 0.f, Q = 0.f;
#pragma unroll
        for (int t = 0; t < 8; ++t) { S += rs[p][t]; Q += rq[p][t]; }
        float mu = S / 256.f;
        float var = Q / 256.f - mu * mu;
        muA[p] = mu; rsA[p] = rsqrtf(var + EPSV);
    }
    __syncthreads();
    int cg = tid >> 5, xi = tid & 31;
    for (int cc = 0; cc < 32; ++cc) {
        int c = cc * 8 + cg;
        float v = (zf[xi][c] - muA[xi]) * rsA[xi] * g[c] + b[c];
        size_t gi = ((size_t)(n * 256 + c) * 128 + y) * 128 + x0 + xi;
        outp[gi] = xin[gi] + v;
    }
}

extern "C" void kernel_launch(void* const* d_in, const int* in_sizes, int n_in,
                              void* d_out, int out_size, void* d_ws, size_t ws_size,
                              hipStream_t stream) {
    (void)in_sizes; (void)n_in; (void)out_size; (void)ws_size;
    const float* x1     = (const float*)d_in[0];
    const float* x2     = (const float*)d_in[1];
    const float* qk_w   = (const float*)d_in[2];
    const float* qk_g   = (const float*)d_in[3];
    const float* qk_b   = (const float*)d_in[4];
    const float* qk_m   = (const float*)d_in[5];
    const float* qk_v   = (const float*)d_in[6];
    const float* v_w    = (const float*)d_in[7];
    const float* v_g    = (const float*)d_in[8];
    const float* v_b    = (const float*)d_in[9];
    const float* v_m    = (const float*)d_in[10];
    const float* v_v    = (const float*)d_in[11];
    const float* ln1_g  = (const float*)d_in[12];
    const float* ln1_b  = (const float*)d_in[13];
    const float* ln2_g  = (const float*)d_in[14];
    const float* ln2_b  = (const float*)d_in[15];
    const float* merge_w = (const float*)d_in[16];
    const float* mlp_w1 = (const float*)d_in[17];
    const float* mlp_w2 = (const float*)d_in[18];

    float* ws      = (float*)d_ws;
    float* pooled  = ws + OFF_P;
    float* qkvbuf  = ws + OFF_Q;     // q,k,v1,v2 contiguous, 1,048,576 apart
    float* v1buf   = ws + OFF_V1;
    float* v2buf   = ws + OFF_V2;
    float* m1buf   = ws + OFF_M1;
    float* m2buf   = ws + OFF_M2;
    float* mgbuf   = ws + OFF_MG;
    float* regA    = ws + OFF_A;     // scores -> z(bf16) -> o (stream-ordered reuse)
    ushort_t* qkb16 = (ushort_t*)(ws + OFF_P);   // q bf16 then k bf16 (pooled dead after dwbn)
    ushort_t* zb16 = (ushort_t*)(ws + OFF_A);
    ushort_t* w1b  = (ushort_t*)(ws + OFF_W1B);
    ushort_t* w2b  = (ushort_t*)(ws + OFF_W2B);
    ushort_t* hid  = (ushort_t*)(ws + OFF_HID);
    float* outp    = (float*)d_out;

    hipMemsetAsync(m2buf, 0, 1048576 * sizeof(float), stream);

    pool_kernel<<<8192, 256, 0, stream>>>(x1, x2, pooled);
    lnc_kernel<<<8192, 256, 0, stream>>>(pooled, ln1_g, ln1_b);
    dwbn_kernel<<<dim3(4096, 4), 256, 0, stream>>>(pooled,
        qk_w, qk_g, qk_b, qk_m, qk_v, v_w, v_g, v_b, v_m, v_v, qkvbuf);
    // q,k (contiguous at OFF_Q..OFF_K) -> bf16 into dead pooled region
    cvt_kernel<<<8192, 256, 0, stream>>>(qkvbuf, qkb16, 2097152);
    qk_mfma<<<dim3(8, 8, 32), 256, 0, stream>>>(qkb16, qkb16 + 1048576, regA);
    m1_kernel<<<dim3(32, 8, 4), 256, 0, stream>>>(regA, v2buf, m1buf);
    m2_kernel<<<dim3(32, 8, 4), 256, 0, stream>>>(regA, v1buf, m2buf);

    // weight conversion (after m1/m2: w1b/w2b live in the dead scores tail)
    cvt_kernel<<<1024, 256, 0, stream>>>(mlp_w1, w1b, 262144);
    cvt_kernel<<<512, 256, 0, stream>>>(mlp_w2, w2b, 131072);

    for (int br = 0; br < 2; ++br) {
        const float* xin = br ? x2 : x1;
        const float* mm  = br ? m2buf : m1buf;
        merge_kernel<<<512, 256, 0, stream>>>(mm, merge_w, mgbuf);
        zbuild_kernel<<<2048, 256, 0, stream>>>(xin, mgbuf, zb16);
        mfma_gemm<<<dim3(512, 4), 256, 0, stream>>>(zb16, w1b, nullptr, hid, 512, 1);
        mfma_gemm<<<dim3(512, 2), 256, 0, stream>>>(hid, w2b, regA, nullptr, 256, 0);
        final_kernel<<<dim3(4, 128, 4), 256, 0, stream>>>(regA, xin, ln2_g, ln2_b,
                                                          outp + (size_t)br * 16777216);
    }
}